// Round 6
// baseline (211.338 us; speedup 1.0000x reference)
//
#include <hip/hip_runtime.h>
#include <hip/hip_bf16.h>

// Shapes: B=8, N=1024, D=768, H=12, HD=64, 3D=2304, tokens M=8192.
// Workspace layout (bytes), total 55,050,240 (~52.5 MiB):
//   xb   @ 0         : [8192][768]  bf16 (x * gate; reused as attn-out later)
//   wtq  @ 12582912  : [2304][768]  bf16 (W_qkv^T)
//   wtm  @ 16121856  : [768][768]   bf16 (W_msa^T)
//   qb   @ 17301504  : [B,H,N,64]   bf16 (q * SCALE * log2e)
//   kb   @ 29884416  : [B,H,N,64]   bf16 (k)
//   vt   @ 42467328  : [B,H,64,N]   bf16 (v, transposed)

typedef __attribute__((ext_vector_type(8))) short bf8;   // 8 x bf16 (4 VGPRs)
typedef __attribute__((ext_vector_type(4))) float f4;

#define QSCALE 0.1803368801111204f  // (1/8) * log2(e): exp2-domain logits
#define MFMA16 __builtin_amdgcn_mfma_f32_16x16x32_bf16

static __device__ __forceinline__ short bf16_of(float f) {
    union { float f; unsigned u; } a; a.f = f;
    unsigned r = a.u + 0x7FFFu + ((a.u >> 16) & 1u);  // RNE
    return (short)(r >> 16);
}

static __device__ __forceinline__ unsigned bfpk(float lo, float hi) {
    float2 t; t.x = lo; t.y = hi;
    __hip_bfloat162 b = __float22bfloat162_rn(t);
    union { __hip_bfloat162 b; unsigned u; } c; c.b = b;
    return c.u;
}

// async global->LDS, 16 bytes/lane. LDS dest must be wave-uniform base + lane*16.
static __device__ __forceinline__ void async16(const short* g, short* l) {
    __builtin_amdgcn_global_load_lds(
        (const __attribute__((address_space(1))) void*)g,
        (__attribute__((address_space(3))) void*)l, 16, 0, 0);
}

// ---- merged prep kernel: cvt (blocks 0..3071) + Wqkv transpose (3072..3503)
//      + Wmsa transpose (3504..3647). Independent work; saves 2 launch gaps.
static __device__ __forceinline__ void transpose64(
        const float* __restrict__ w, short* __restrict__ wt,
        int K, int E, int k0, int e0, int tid, short (*t)[65]) {
#pragma unroll
    for (int p = 0; p < 16; ++p) {
        int idx = p * 256 + tid;
        int r = idx >> 6, c = idx & 63;
        t[r][c] = bf16_of(w[(k0 + r) * E + e0 + c]);
    }
    __syncthreads();
#pragma unroll
    for (int p = 0; p < 16; ++p) {
        int idx = p * 256 + tid;
        int r = idx >> 6, c = idx & 63;     // r = e offset, c = k offset
        wt[(e0 + r) * K + k0 + c] = t[c][r];
    }
}

__global__ __launch_bounds__(256) void k_prep(
        const float* __restrict__ x, const float* __restrict__ gate,
        short* __restrict__ xb,
        const float* __restrict__ Wqkv, short* __restrict__ wtq,
        const float* __restrict__ Wmsa, short* __restrict__ wtm) {
    __shared__ short t[64][65];
    const int bid = blockIdx.x, tid = threadIdx.x;
    if (bid < 3072) {
        int i = bid * 256 + tid;              // 786432 = 8192*768/8 exactly
        const float g = gate[i / 96];         // row = i*8/768
        const f4* sp = (const f4*)x;
        f4 a = sp[2 * i], b = sp[2 * i + 1];
        union { bf8 v; short h[8]; } o;
        o.h[0] = bf16_of(a[0] * g); o.h[1] = bf16_of(a[1] * g);
        o.h[2] = bf16_of(a[2] * g); o.h[3] = bf16_of(a[3] * g);
        o.h[4] = bf16_of(b[0] * g); o.h[5] = bf16_of(b[1] * g);
        o.h[6] = bf16_of(b[2] * g); o.h[7] = bf16_of(b[3] * g);
        ((bf8*)xb)[i] = o.v;
    } else if (bid < 3504) {
        int tt = bid - 3072;                  // 432 = 36 x 12
        transpose64(Wqkv, wtq, 768, 2304, (tt / 36) * 64, (tt % 36) * 64, tid, t);
    } else {
        int tt = bid - 3504;                  // 144 = 12 x 12
        transpose64(Wmsa, wtm, 768, 768, (tt / 12) * 64, (tt % 12) * 64, tid, t);
    }
}

// ---- 128x128 2-phase GEMM mainloop (kept for k_gemm_final: its 384 blocks
// are fully co-resident at 2 blocks/CU).
static __device__ __forceinline__ void gemm128(const short* __restrict__ gA,
                                               const short* __restrict__ gB,
                                               short* smem,
                                               f4 acc[4][4]) {
    const int tid = threadIdx.x, lane = tid & 63;
    const int l16 = lane & 15, quad = lane >> 4, rx = l16 & 7;
    const int wm = (tid >> 6) & 1, wn = tid >> 7;

    auto stage = [&](short* S, int k0) {
#pragma unroll
        for (int c = 0; c < 4; ++c) {
            int p = c * 256 + tid;
            int row = p >> 3, slot = p & 7;
            int gc = slot ^ (row & 7);
            async16(gA + row * 768 + k0 + gc * 8, S + p * 8);
            async16(gB + row * 768 + k0 + gc * 8, S + 8192 + p * 8);
        }
    };

    stage(smem, 0);
    for (int it = 0; it < 12; ++it) {
        __builtin_amdgcn_s_waitcnt(0);   // own DMA for tile[it] drained
        __syncthreads();                 // => tile[it] resident for all waves
        short* Sc = smem + (it & 1) * 16384;
        if (it + 1 < 12) stage(smem + ((it + 1) & 1) * 16384, (it + 1) * 64);
        const short* As = Sc;
        const short* Bs = Sc + 8192;
#pragma unroll
        for (int ks = 0; ks < 2; ++ks) {
            bf8 af[4], bfr[4];
#pragma unroll
            for (int mt = 0; mt < 4; ++mt)
                af[mt] = *(const bf8*)(As + (wm * 64 + mt * 16 + l16) * 64 +
                                       (((ks * 4 + quad) ^ rx) * 8));
#pragma unroll
            for (int nt = 0; nt < 4; ++nt)
                bfr[nt] = *(const bf8*)(Bs + (wn * 64 + nt * 16 + l16) * 64 +
                                        (((ks * 4 + quad) ^ rx) * 8));
#pragma unroll
            for (int mt = 0; mt < 4; ++mt)
#pragma unroll
                for (int nt = 0; nt < 4; ++nt)
                    acc[mt][nt] = MFMA16(af[mt], bfr[nt], acc[mt][nt], 0, 0, 0);
        }
    }
    __syncthreads();   // callers may reuse smem right after return
}

// ---- QKV projection: [8192,768] @ [768,2304].
// GEOMETRY CHANGE (rounds 3-5 post-mortem): per-lane acc=144 at the 256x288
// tile is structurally unallocatable (two liveness-reorder attempts both left
// ~6.5MB scratch traffic). New tile 128x288, BK=32:
//   grid 64m x 8n = 512 blocks = EXACTLY 2 blocks/CU (no tail, cross-block
//   barrier hiding); 8 waves as 4M x 2N -> per-wave 32x144 = acc[2][9] = 72
//   regs; launch_bounds(512,4) targets <=128 VGPR for true 2-block residency.
// LDS: TRIPLE buffer, 3 x 13312 shorts = 78 KiB (2 blocks x 78K <= 160K/CU).
//   Per buf: A = 512 chunks (128 rows x 4 slots of 16B), B = 1152 chunks
//   (288 x 4) at +4096 shorts. Chunk p holds k-slot g=(p&3)^((row>>1)&3),
//   row=p>>2 -> frag ds_read_b128 chunks are uniform mod 8 = conflict-free.
// Pipeline: stage(t+2) while computing t; per-wave counted vmcnt (waves 0-1
//   issue 4 loads/tile, others 3) -> vmcnt(4|3) per tile, vmcnt(0) only at
//   t==22. One barrier per K-tile; reads are MFMA-consumed before it (lgkm
//   enforced by use), so the DMA overwrite of buf (t-1)%3 at iter t+? is safe.
// Per K-tile per wave: 11 ds_read_b128, 18 MFMA, nf-split (5+4) read groups
//   to cap frag liveness (~28 regs).
__global__ __launch_bounds__(512, 4) void k_gemm_qkv(
        const short* __restrict__ xb, const short* __restrict__ wtq,
        short* __restrict__ qb, short* __restrict__ kb, short* __restrict__ vt) {
    __shared__ short lds[39936];   // 3 x 13312 shorts = 78 KiB
    const int tid = threadIdx.x, lane = tid & 63;
    const int l16 = lane & 15, quad = lane >> 4;
    const int wv = tid >> 6, wm = wv >> 1, wn = wv & 1;   // 4M x 2N waves

    // XCD swizzle: 512 blocks = 8 XCDs x 64; each XCD: 8 mI x all 8 nI
    // (A-panels L2-local per XCD; B 3.5MB ~ one XCD L2/L3).
    const int wg = blockIdx.x;
    const int swz = (wg & 7) * 64 + (wg >> 3);
    const int mI = swz >> 3, nI = swz & 7;
    const int m0 = mI * 128, n0 = nI * 288;

    const short* gA = xb + m0 * 768;
    const short* gB = wtq + n0 * 768;

    auto stage = [&](int buf, int k0) {
        short* base = lds + buf * 13312;
        {   // A: 1 chunk/thread
            int p = tid, row = p >> 2;
            int g = (p & 3) ^ ((row >> 1) & 3);
            async16(gA + row * 768 + k0 + g * 8, base + p * 8);
        }
#pragma unroll
        for (int j = 0; j < 2; ++j) {   // B: 2 chunks/thread
            int p = j * 512 + tid, row = p >> 2;
            int g = (p & 3) ^ ((row >> 1) & 3);
            async16(gB + row * 768 + k0 + g * 8, base + 4096 + p * 8);
        }
        if (tid < 128) {                // B: extra 128 chunks (waves 0-1)
            int p = 1024 + tid, row = p >> 2;
            int g = (p & 3) ^ ((row >> 1) & 3);
            async16(gB + row * 768 + k0 + g * 8, base + 4096 + p * 8);
        }
    };

    auto rdA = [&](const short* base, int mf) {
        int row = wm * 32 + mf * 16 + l16;
        int c = row * 4 + (quad ^ ((row >> 1) & 3));
        return *(const bf8*)(base + c * 8);
    };
    auto rdB = [&](const short* base, int nf) {
        int row = wn * 144 + nf * 16 + l16;
        int c = row * 4 + (quad ^ ((row >> 1) & 3));
        return *(const bf8*)(base + 4096 + c * 8);
    };

    f4 z = {0.f, 0.f, 0.f, 0.f};
    f4 acc[2][9];
#pragma unroll
    for (int mf = 0; mf < 2; ++mf)
#pragma unroll
        for (int nf = 0; nf < 9; ++nf) acc[mf][nf] = z;

    // prologue: stage tiles 0 and 1; wait for tile 0 (leave tile 1 in flight)
    stage(0, 0); stage(1, 32);
    if (wv < 2) asm volatile("s_waitcnt vmcnt(4)" ::: "memory");
    else        asm volatile("s_waitcnt vmcnt(3)" ::: "memory");
    __builtin_amdgcn_s_barrier();

#pragma unroll 3
    for (int t = 0; t < 24; ++t) {
        const short* cur = lds + (t % 3) * 13312;
        bf8 af[2];
        af[0] = rdA(cur, 0); af[1] = rdA(cur, 1);
        bf8 bfr[5];
#pragma unroll
        for (int nf = 0; nf < 5; ++nf) bfr[nf] = rdB(cur, nf);
        if (t < 22) stage((t + 2) % 3, (t + 2) * 32);
        __builtin_amdgcn_s_setprio(1);
#pragma unroll
        for (int mf = 0; mf < 2; ++mf)
#pragma unroll
            for (int nf = 0; nf < 5; ++nf)
                acc[mf][nf] = MFMA16(af[mf], bfr[nf], acc[mf][nf], 0, 0, 0);
        __builtin_amdgcn_s_setprio(0);
        bf8 bfh[4];
#pragma unroll
        for (int nf = 0; nf < 4; ++nf) bfh[nf] = rdB(cur, nf + 5);
        __builtin_amdgcn_s_setprio(1);
#pragma unroll
        for (int mf = 0; mf < 2; ++mf)
#pragma unroll
            for (int nf = 0; nf < 4; ++nf)
                acc[mf][nf + 5] = MFMA16(af[mf], bfh[nf], acc[mf][nf + 5], 0, 0, 0);
        __builtin_amdgcn_s_setprio(0);
        // drain all but this iteration's stage -> tile t+1 resident at barrier
        if (t < 22) {
            if (wv < 2) asm volatile("s_waitcnt vmcnt(4)" ::: "memory");
            else        asm volatile("s_waitcnt vmcnt(3)" ::: "memory");
        } else if (t == 22) {
            asm volatile("s_waitcnt vmcnt(0)" ::: "memory");
        }
        __builtin_amdgcn_s_barrier();
    }

    // ---------------- epilogue ----------------
    const int bI = m0 >> 10, nn0 = m0 & 1023;
    // q/k frags: direct coalesced-ish stores (frags never straddle q/k/v)
#pragma unroll
    for (int nf = 0; nf < 9; ++nf) {
        const int ct = n0 + wn * 144 + nf * 16;
        if (ct < 1536) {
            const int which = (ct >= 768) ? 1 : 0;
            const int h = (ct - which * 768) >> 6;
            const int hd = (ct & 63) + l16;
            short* dst = (which ? kb : qb) + (bI * 12 + h) * 65536 + hd;
#pragma unroll
            for (int mf = 0; mf < 2; ++mf)
#pragma unroll
                for (int r = 0; r < 4; ++r) {
                    const int nn = nn0 + wm * 32 + mf * 16 + quad * 4 + r;
                    const float val = acc[mf][nf][r];
                    dst[nn * 64] = bf16_of(which ? val : val * QSCALE);
                }
        }
    }
    // v frags: transpose through LDS in 96-col passes (96 x 136 shorts)
    const int vstart = (n0 >= 1536) ? n0 : 1536;
    const int npass = (n0 + 288 > vstart) ? (n0 + 288 - vstart) / 96 : 0;
    for (int p = 0; p < npass; ++p) {
        __syncthreads();
        const int c0 = vstart + p * 96;
#pragma unroll
        for (int nf = 0; nf < 9; ++nf) {
            const int ct = n0 + wn * 144 + nf * 16;
            if (ct >= c0 && ct < c0 + 96) {
                const int lc = ct - c0 + l16;
#pragma unroll
                for (int mf = 0; mf < 2; ++mf)
#pragma unroll
                    for (int r = 0; r < 4; ++r) {
                        const int rl = wm * 32 + mf * 16 + quad * 4 + r;
                        lds[lc * 136 + rl] = bf16_of(acc[mf][nf][r]);
                    }
            }
        }
        __syncthreads();
        const int vg0 = c0 - 1536;
#pragma unroll
        for (int u = 0; u < 3; ++u) {
            const int idx = u * 512 + tid;       // 96 cols x 16 chunks
            const int lc = idx >> 4, ck = idx & 15;
            const int vg = vg0 + lc;
            const int h = vg >> 6, hd = vg & 63;
            bf8 vv = *(const bf8*)(lds + lc * 136 + ck * 8);
            *(bf8*)(vt + ((bI * 12 + h) * 64 + hd) * 1024 + nn0 + ck * 8) = vv;
        }
    }
}

// ---- final projection: [8192,768] @ [768,768] + bias -> fp32 out ----
__global__ __launch_bounds__(256) void k_gemm_final(
        const short* __restrict__ attn, const short* __restrict__ wtm,
        const float* __restrict__ bias, float* __restrict__ out) {
    __shared__ short smem[32768];
    const int lane = threadIdx.x & 63;
    const int l16 = lane & 15, quad = lane >> 4;
    const int wm = (threadIdx.x >> 6) & 1, wn = threadIdx.x >> 7;
    const int m0 = blockIdx.y * 128, n0 = blockIdx.x * 128;
    f4 z = {0.f, 0.f, 0.f, 0.f};
    f4 acc[4][4] = {{z,z,z,z},{z,z,z,z},{z,z,z,z},{z,z,z,z}};
    gemm128(attn + m0 * 768, wtm + n0 * 768, smem, acc);
#pragma unroll
    for (int mt = 0; mt < 4; ++mt) {
#pragma unroll
        for (int r = 0; r < 4; ++r) {
            const int row = m0 + wm * 64 + mt * 16 + quad * 4 + r;
#pragma unroll
            for (int nt = 0; nt < 4; ++nt) {
                const int e = n0 + wn * 64 + nt * 16 + l16;
                out[row * 768 + e] = acc[mt][nt][r] + bias[e];
            }
        }
    }
}

// ---- flash attention: 4 waves x 32 q-rows (256-thread block), grid (96,8)
//      = 768 blocks -> exactly 3 co-resident blocks/CU (launch_bounds(256,3)).
// Two q-groups per wave SHARE the K and V LDS fragments: ds_read per MFMA
// halves, per-wave ILP doubles, barrier cost per unit work halves.
// S-MFMA set A uses K rows sigma(p)=8*(p>>2)+(p&3), set B rows sigma(p)+4.
// lane(l16,quad) regs [A0..A3,B0..B3] = P[m=l16][j=quad*8+0..7]: the PV
// B-operand directly -- no cross-lane transform needed.
// LDS swizzle f(row)=4*((row>>3)&1)+(row&3) keeps sigma-reads at 2 lanes/bank.
__global__ __launch_bounds__(256, 3) void k_attn(const short* __restrict__ qb,
                                                 const short* __restrict__ kb,
                                                 const short* __restrict__ vt,
                                                 short* __restrict__ attn) {
    __shared__ short Ks[2][4096];     // [64 keys][8 slots], f-swizzled
    __shared__ short Vs[2][4096];     // [64 dims][8 slots], f-swizzled
    const int tid = threadIdx.x, wave = tid >> 6, lane = tid & 63;
    const int l16 = lane & 15, quad = lane >> 4;
    const int bh = blockIdx.x;             // b*12 + h
    const int b = bh / 12, h = bh - b * 12;
    const int m_base = blockIdx.y * 128 + wave * 32;  // 32 q-rows per wave
    const short* qh = qb + bh * 65536;
    const short* kh = kb + bh * 65536;
    const short* vh = vt + bh * 65536;     // [64][1024]

    // K-read offsets: set A row rA = sigma(l16), set B row rA+4 (f identical)
    const int rA = ((l16 >> 2) << 3) + (l16 & 3);
    const int fK = (((rA >> 3) & 1) << 2) + (rA & 3);
    const int sK = (quad ^ fK) * 8;              // slot*8 for d-chunk=quad
    const int oAlo = rA * 64 + sK;               // d 0..31
    const int oAhi = rA * 64 + (sK ^ 32);        // d 32..63 (slot^4)
    const int oBlo = oAlo + 256, oBhi = oAhi + 256;  // row+4
    // V-read offset: row = dt*16+l16, chunk = (jj>>3)+quad
    const int fV = (((l16 >> 3) & 1) << 2) + (l16 & 3);
    const int oV = l16 * 64 + ((quad ^ fV) * 8); // jj=32 -> ^32

    // Q^T b-frags for both 16-row groups (fixed for whole loop)
    const short* qp0 = qh + (m_base + l16) * 64 + quad * 8;
    bf8 qf00 = *(const bf8*)(qp0);
    bf8 qf01 = *(const bf8*)(qp0 + 32);
    const short* qp1 = qp0 + 16 * 64;
    bf8 qf10 = *(const bf8*)(qp1);
    bf8 qf11 = *(const bf8*)(qp1 + 32);

    union { bf8 v; short h[8]; } onef;
#pragma unroll
    for (int i = 0; i < 8; ++i) onef.h[i] = (short)0x3F80;  // bf16 1.0

    f4 z = {0.f, 0.f, 0.f, 0.f};
    f4 acc0[4] = {z, z, z, z};             // out^T group 0: 4 d-tiles
    f4 acc1[4] = {z, z, z, z};             // out^T group 1
    f4 accl0 = z, accl1 = z;               // P row-sums via ones-MFMA

    auto stage = [&](int buf, int j0) {
        // 256 threads x 2: 512 chunks each for K and V
#pragma unroll
        for (int j = 0; j < 2; ++j) {
            int idx = j * 256 + tid;
            int row = idx >> 3;
            int fr = (((row >> 3) & 1) << 2) + (row & 3);
            int gc = (idx & 7) ^ fr;        // slot idx&7 holds chunk gc
            async16(kh + (j0 + row) * 64 + gc * 8, Ks[buf] + idx * 8);
            async16(vh + row * 1024 + j0 + gc * 8, Vs[buf] + idx * 8);
        }
    };

    stage(0, 0);
    int cur = 0;
    for (int it = 0; it < 16; ++it) {
        __builtin_amdgcn_s_waitcnt(0);         // own DMA for tile[cur] drained
        __syncthreads();                       // => tile[cur] resident for all
        if (it + 1 < 16) stage(cur ^ 1, (it + 1) * 64);  // overlaps compute
        const short* Kc = Ks[cur];
        const short* Vc = Vs[cur];

#pragma unroll
        for (int jj = 0; jj < 64; jj += 32) {
            const short* kjj = Kc + jj * 64;
            bf8 kAlo = *(const bf8*)(kjj + oAlo);
            bf8 kAhi = *(const bf8*)(kjj + oAhi);
            bf8 kBlo = *(const bf8*)(kjj + oBlo);
            bf8 kBhi = *(const bf8*)(kjj + oBhi);
            bf8 vf0 = *(const bf8*)(Vc + 0 * 1024 + (oV ^ (jj ? 32 : 0)));
            bf8 vf1 = *(const bf8*)(Vc + 1 * 1024 + (oV ^ (jj ? 32 : 0)));
            bf8 vf2 = *(const bf8*)(Vc + 2 * 1024 + (oV ^ (jj ? 32 : 0)));
            bf8 vf3 = *(const bf8*)(Vc + 3 * 1024 + (oV ^ (jj ? 32 : 0)));

            // ----- group 0 -----
            {
                f4 sA = z, sB = z;
                sA = MFMA16(kAlo, qf00, sA, 0, 0, 0);
                sA = MFMA16(kAhi, qf01, sA, 0, 0, 0);
                sB = MFMA16(kBlo, qf00, sB, 0, 0, 0);
                sB = MFMA16(kBhi, qf01, sB, 0, 0, 0);
                float a0 = __builtin_amdgcn_exp2f(sA[0]);
                float a1 = __builtin_amdgcn_exp2f(sA[1]);
                float a2 = __builtin_amdgcn_exp2f(sA[2]);
                float a3 = __builtin_amdgcn_exp2f(sA[3]);
                float b0 = __builtin_amdgcn_exp2f(sB[0]);
                float b1 = __builtin_amdgcn_exp2f(sB[1]);
                float b2 = __builtin_amdgcn_exp2f(sB[2]);
                float b3 = __builtin_amdgcn_exp2f(sB[3]);
                union { bf8 v; unsigned u[4]; } p;
                p.u[0] = bfpk(a0, a1); p.u[1] = bfpk(a2, a3);
                p.u[2] = bfpk(b0, b1); p.u[3] = bfpk(b2, b3);
                accl0 = MFMA16(onef.v, p.v, accl0, 0, 0, 0);
                acc0[0] = MFMA16(vf0, p.v, acc0[0], 0, 0, 0);
                acc0[1] = MFMA16(vf1, p.v, acc0[1], 0, 0, 0);
                acc0[2] = MFMA16(vf2, p.v, acc0[2], 0, 0, 0);
                acc0[3] = MFMA16(vf3, p.v, acc0[3], 0, 0, 0);
            }
            // ----- group 1 (shares kA/kB/vf frags) -----
            {
                f4 sA = z, sB = z;
                sA = MFMA16(kAlo, qf10, sA, 0, 0, 0);
                sA = MFMA16(kAhi, qf11, sA, 0, 0, 0);
                sB = MFMA16(kBlo, qf10, sB, 0, 0, 0);
                sB = MFMA16(kBhi, qf11, sB, 0, 0, 0);
                float a0 = __builtin_amdgcn_exp2f(sA[0]);
                float a1 = __builtin_amdgcn_exp2f(sA[1]);
                float a2 = __builtin_amdgcn_exp2f(sA[2]);
                float a3 = __builtin_amdgcn_exp2f(sA[3]);
                float b0 = __builtin_amdgcn_exp2f(sB[0]);
                float b1 = __builtin_amdgcn_exp2f(sB[1]);
                float b2 = __builtin_amdgcn_exp2f(sB[2]);
                float b3 = __builtin_amdgcn_exp2f(sB[3]);
                union { bf8 v; unsigned u[4]; } p;
                p.u[0] = bfpk(a0, a1); p.u[1] = bfpk(a2, a3);
                p.u[2] = bfpk(b0, b1); p.u[3] = bfpk(b2, b3);
                accl1 = MFMA16(onef.v, p.v, accl1, 0, 0, 0);
                acc1[0] = MFMA16(vf0, p.v, acc1[0], 0, 0, 0);
                acc1[1] = MFMA16(vf1, p.v, acc1[1], 0, 0, 0);
                acc1[2] = MFMA16(vf2, p.v, acc1[2], 0, 0, 0);
                acc1[3] = MFMA16(vf3, p.v, acc1[3], 0, 0, 0);
            }
        }
        cur ^= 1;
    }

    const float inv0 = 1.f / accl0[0];
    const float inv1 = 1.f / accl1[0];
    const int row0 = (b << 10) + m_base + l16;
    short* op0 = attn + row0 * 768 + h * 64 + quad * 4;
    short* op1 = op0 + 16 * 768;
#pragma unroll
    for (int dt = 0; dt < 4; ++dt)
#pragma unroll
        for (int r = 0; r < 4; ++r) {
            op0[dt * 16 + r] = bf16_of(acc0[dt][r] * inv0);
            op1[dt * 16 + r] = bf16_of(acc1[dt][r] * inv1);
        }
}

extern "C" void kernel_launch(void* const* d_in, const int* in_sizes, int n_in,
                              void* d_out, int out_size, void* d_ws, size_t ws_size,
                              hipStream_t stream) {
    const float* x    = (const float*)d_in[0];   // [8,1024,768]
    const float* gate = (const float*)d_in[1];   // [8,1024]
    const float* Wqkv = (const float*)d_in[2];   // [768,2304]
    const float* Wmsa = (const float*)d_in[3];   // [768,768]
    const float* bmsa = (const float*)d_in[4];   // [768]
    float* out = (float*)d_out;

    char* ws = (char*)d_ws;
    short* xb  = (short*)(ws);
    short* wtq = (short*)(ws + 12582912);
    short* wtm = (short*)(ws + 16121856);
    short* qb  = (short*)(ws + 17301504);
    short* kb  = (short*)(ws + 29884416);
    short* vt  = (short*)(ws + 42467328);
    short* attn = xb;  // xb fully consumed by k_gemm_qkv before k_attn writes

    k_prep<<<3648, 256, 0, stream>>>(x, gate, xb, Wqkv, wtq, Wmsa, wtm);
    k_gemm_qkv<<<512, 512, 0, stream>>>(xb, wtq, qb, kb, vt);
    k_attn<<<dim3(96, 8), 256, 0, stream>>>(qb, kb, vt, attn);
    k_gemm_final<<<dim3(6, 64), 256, 0, stream>>>(attn, wtm, bmsa, out);
}

// Round 7
// 186.485 us; speedup vs baseline: 1.1333x; 1.1333x over previous
//
#include <hip/hip_runtime.h>
#include <hip/hip_bf16.h>

// Shapes: B=8, N=1024, D=768, H=12, HD=64, 3D=2304, tokens M=8192.
// Workspace layout (bytes), total 55,050,240 (~52.5 MiB):
//   xb   @ 0         : [8192][768]  bf16 (x * gate; reused as attn-out later)
//   wtq  @ 12582912  : [2304][768]  bf16 (W_qkv^T)
//   wtm  @ 16121856  : [768][768]   bf16 (W_msa^T)
//   qb   @ 17301504  : [B,H,N,64]   bf16 (q * SCALE * log2e)
//   kb   @ 29884416  : [B,H,N,64]   bf16 (k)
//   vt   @ 42467328  : [B,H,64,N]   bf16 (v, transposed)

typedef __attribute__((ext_vector_type(8))) short bf8;   // 8 x bf16 (4 VGPRs)
typedef __attribute__((ext_vector_type(4))) float f4;

#define QSCALE 0.1803368801111204f  // (1/8) * log2(e): exp2-domain logits
#define MFMA16 __builtin_amdgcn_mfma_f32_16x16x32_bf16

static __device__ __forceinline__ short bf16_of(float f) {
    union { float f; unsigned u; } a; a.f = f;
    unsigned r = a.u + 0x7FFFu + ((a.u >> 16) & 1u);  // RNE
    return (short)(r >> 16);
}

static __device__ __forceinline__ unsigned bfpk(float lo, float hi) {
    float2 t; t.x = lo; t.y = hi;
    __hip_bfloat162 b = __float22bfloat162_rn(t);
    union { __hip_bfloat162 b; unsigned u; } c; c.b = b;
    return c.u;
}

// async global->LDS, 16 bytes/lane. LDS dest must be wave-uniform base + lane*16.
static __device__ __forceinline__ void async16(const short* g, short* l) {
    __builtin_amdgcn_global_load_lds(
        (const __attribute__((address_space(1))) void*)g,
        (__attribute__((address_space(3))) void*)l, 16, 0, 0);
}

// ---- merged prep kernel: cvt (blocks 0..3071) + Wqkv transpose (3072..3503)
//      + Wmsa transpose (3504..3647). Independent work; saves 2 launch gaps.
static __device__ __forceinline__ void transpose64(
        const float* __restrict__ w, short* __restrict__ wt,
        int K, int E, int k0, int e0, int tid, short (*t)[65]) {
#pragma unroll
    for (int p = 0; p < 16; ++p) {
        int idx = p * 256 + tid;
        int r = idx >> 6, c = idx & 63;
        t[r][c] = bf16_of(w[(k0 + r) * E + e0 + c]);
    }
    __syncthreads();
#pragma unroll
    for (int p = 0; p < 16; ++p) {
        int idx = p * 256 + tid;
        int r = idx >> 6, c = idx & 63;     // r = e offset, c = k offset
        wt[(e0 + r) * K + k0 + c] = t[c][r];
    }
}

__global__ __launch_bounds__(256) void k_prep(
        const float* __restrict__ x, const float* __restrict__ gate,
        short* __restrict__ xb,
        const float* __restrict__ Wqkv, short* __restrict__ wtq,
        const float* __restrict__ Wmsa, short* __restrict__ wtm) {
    __shared__ short t[64][65];
    const int bid = blockIdx.x, tid = threadIdx.x;
    if (bid < 3072) {
        int i = bid * 256 + tid;              // 786432 = 8192*768/8 exactly
        const float g = gate[i / 96];         // row = i*8/768
        const f4* sp = (const f4*)x;
        f4 a = sp[2 * i], b = sp[2 * i + 1];
        union { bf8 v; short h[8]; } o;
        o.h[0] = bf16_of(a[0] * g); o.h[1] = bf16_of(a[1] * g);
        o.h[2] = bf16_of(a[2] * g); o.h[3] = bf16_of(a[3] * g);
        o.h[4] = bf16_of(b[0] * g); o.h[5] = bf16_of(b[1] * g);
        o.h[6] = bf16_of(b[2] * g); o.h[7] = bf16_of(b[3] * g);
        ((bf8*)xb)[i] = o.v;
    } else if (bid < 3504) {
        int tt = bid - 3072;                  // 432 = 36 x 12
        transpose64(Wqkv, wtq, 768, 2304, (tt / 36) * 64, (tt % 36) * 64, tid, t);
    } else {
        int tt = bid - 3504;                  // 144 = 12 x 12
        transpose64(Wmsa, wtm, 768, 768, (tt / 12) * 64, (tt % 12) * 64, tid, t);
    }
}

// ---- 128x128 2-phase GEMM mainloop (kept for k_gemm_final: its 384 blocks
// are fully co-resident at 2 blocks/CU).
static __device__ __forceinline__ void gemm128(const short* __restrict__ gA,
                                               const short* __restrict__ gB,
                                               short* smem,
                                               f4 acc[4][4]) {
    const int tid = threadIdx.x, lane = tid & 63;
    const int l16 = lane & 15, quad = lane >> 4, rx = l16 & 7;
    const int wm = (tid >> 6) & 1, wn = tid >> 7;

    auto stage = [&](short* S, int k0) {
#pragma unroll
        for (int c = 0; c < 4; ++c) {
            int p = c * 256 + tid;
            int row = p >> 3, slot = p & 7;
            int gc = slot ^ (row & 7);
            async16(gA + row * 768 + k0 + gc * 8, S + p * 8);
            async16(gB + row * 768 + k0 + gc * 8, S + 8192 + p * 8);
        }
    };

    stage(smem, 0);
    for (int it = 0; it < 12; ++it) {
        __builtin_amdgcn_s_waitcnt(0);   // own DMA for tile[it] drained
        __syncthreads();                 // => tile[it] resident for all waves
        short* Sc = smem + (it & 1) * 16384;
        if (it + 1 < 12) stage(smem + ((it + 1) & 1) * 16384, (it + 1) * 64);
        const short* As = Sc;
        const short* Bs = Sc + 8192;
#pragma unroll
        for (int ks = 0; ks < 2; ++ks) {
            bf8 af[4], bfr[4];
#pragma unroll
            for (int mt = 0; mt < 4; ++mt)
                af[mt] = *(const bf8*)(As + (wm * 64 + mt * 16 + l16) * 64 +
                                       (((ks * 4 + quad) ^ rx) * 8));
#pragma unroll
            for (int nt = 0; nt < 4; ++nt)
                bfr[nt] = *(const bf8*)(Bs + (wn * 64 + nt * 16 + l16) * 64 +
                                        (((ks * 4 + quad) ^ rx) * 8));
#pragma unroll
            for (int mt = 0; mt < 4; ++mt)
#pragma unroll
                for (int nt = 0; nt < 4; ++nt)
                    acc[mt][nt] = MFMA16(af[mt], bfr[nt], acc[mt][nt], 0, 0, 0);
        }
    }
    __syncthreads();   // callers may reuse smem right after return
}

// ---- QKV projection: [8192,768] @ [768,2304], tile 128x288, BK=64.
// ROUND-6 LESSON: launch_bounds(512,4) (128-reg budget) made the allocator
// split 64 VGPR + 64 AGPR; acc=72 > 64 AGPR -> 63MB scratch. Registers must
// fit the PROVEN (512,2) regime: 256-reg budget, acc[2][9]=72 AGPR + ~90 VGPR.
// Geometry: grid 64m x 8n = 512 blocks = exactly TWO full 256-block rounds
// (zero partial tail; LDS 156KB caps at 1 block/CU anyway).
// 8 waves as 4M x 2N -> per-wave 32x144 output = acc[2][9] = 72 regs.
// LDS: TRIPLE buffer, 3 x 26624 shorts (=156 KiB): per buf A 128x64 (8192)
//   + B 288x64 (18432). R1's proven slot^(row&7) XOR swizzle (2 lanes/bank).
// Pipeline: stage(t+2) during tile t; per-wave counted vmcnt(7|6) per tile
//   (waves 0-3 issue 7 chunks/tile: A2+B5; waves 4-7: 6), vmcnt(0) only at
//   t==10; ONE barrier per K-tile (12 total). Buf written during tile t+1 is
//   (t+3)%3 == t%3 == cur, issued only after the end-of-tile-t barrier: safe.
// Per K-tile per wave: 22 ds_read_b128, 36 MFMA (20+16 in two setprio bursts).
__global__ __launch_bounds__(512, 2) void k_gemm_qkv(
        const short* __restrict__ xb, const short* __restrict__ wtq,
        short* __restrict__ qb, short* __restrict__ kb, short* __restrict__ vt) {
    __shared__ short lds[79872];   // 3 x 26624 shorts = 156 KiB
    const int tid = threadIdx.x, lane = tid & 63;
    const int l16 = lane & 15, quad = lane >> 4, rx = l16 & 7;
    const int wv = tid >> 6, wm = wv >> 1, wn = wv & 1;   // 4M x 2N waves

    // XCD swizzle: 512 blocks = 8 XCDs x 64; each XCD: 8 mI x all 8 nI.
    const int wg = blockIdx.x;
    const int swz = (wg & 7) * 64 + (wg >> 3);
    const int mI = swz >> 3, nI = swz & 7;
    const int m0 = mI * 128, n0 = nI * 288;

    const short* gA = xb + m0 * 768;
    const short* gB = wtq + n0 * 768;

    // stage A half: 128x64 = 1024 chunks (2/thread)
    auto stageA = [&](int buf, int k0) {
        short* base = lds + buf * 26624;
#pragma unroll
        for (int j = 0; j < 2; ++j) {
            int p = j * 512 + tid, row = p >> 3;
            int gc = (p & 7) ^ (row & 7);
            async16(gA + row * 768 + k0 + gc * 8, base + p * 8);
        }
    };
    // stage B half: 288x64 = 2304 chunks (4/thread + 1 extra for tid<256)
    auto stageB = [&](int buf, int k0) {
        short* base = lds + buf * 26624 + 8192;
#pragma unroll
        for (int j = 0; j < 4; ++j) {
            int p = j * 512 + tid, row = p >> 3;
            int gc = (p & 7) ^ (row & 7);
            async16(gB + row * 768 + k0 + gc * 8, base + p * 8);
        }
        if (tid < 256) {
            int p = 2048 + tid, row = p >> 3;
            int gc = (p & 7) ^ (row & 7);
            async16(gB + row * 768 + k0 + gc * 8, base + p * 8);
        }
    };

    auto rdA = [&](const short* base, int mf, int ks) {
        return *(const bf8*)(base + (wm * 32 + mf * 16 + l16) * 64 +
                             (((ks * 4 + quad) ^ rx) << 3));
    };
    auto rdB = [&](const short* base, int nf, int ks) {
        return *(const bf8*)(base + 8192 + (wn * 144 + nf * 16 + l16) * 64 +
                             (((ks * 4 + quad) ^ rx) << 3));
    };

    f4 z = {0.f, 0.f, 0.f, 0.f};
    f4 acc[2][9];
#pragma unroll
    for (int mf = 0; mf < 2; ++mf)
#pragma unroll
        for (int nf = 0; nf < 9; ++nf) acc[mf][nf] = z;

    // prologue: stage tiles 0 and 1; wait tile 0 (leave tile 1's 7|6 in flight)
    stageA(0, 0); stageB(0, 0);
    stageA(1, 64); stageB(1, 64);
    if (wv < 4) asm volatile("s_waitcnt vmcnt(7)" ::: "memory");
    else        asm volatile("s_waitcnt vmcnt(6)" ::: "memory");
    __builtin_amdgcn_s_barrier();

#pragma unroll 3
    for (int t = 0; t < 12; ++t) {
        const short* cur = lds + (t % 3) * 26624;
        // ---- phase 1: nf 0-4 ----
        bf8 af[2][2];
        af[0][0] = rdA(cur, 0, 0); af[0][1] = rdA(cur, 0, 1);
        af[1][0] = rdA(cur, 1, 0); af[1][1] = rdA(cur, 1, 1);
        bf8 bfr[5][2];
#pragma unroll
        for (int nf = 0; nf < 5; ++nf) { bfr[nf][0] = rdB(cur, nf, 0); bfr[nf][1] = rdB(cur, nf, 1); }
        if (t < 10) stageA((t + 2) % 3, (t + 2) * 64);
        __builtin_amdgcn_s_setprio(1);
#pragma unroll
        for (int mf = 0; mf < 2; ++mf)
#pragma unroll
            for (int nf = 0; nf < 5; ++nf) {
                acc[mf][nf] = MFMA16(af[mf][0], bfr[nf][0], acc[mf][nf], 0, 0, 0);
                acc[mf][nf] = MFMA16(af[mf][1], bfr[nf][1], acc[mf][nf], 0, 0, 0);
            }
        __builtin_amdgcn_s_setprio(0);
        // ---- phase 2: nf 5-8 ----
        bf8 bfh[4][2];
#pragma unroll
        for (int nf = 0; nf < 4; ++nf) { bfh[nf][0] = rdB(cur, nf + 5, 0); bfh[nf][1] = rdB(cur, nf + 5, 1); }
        if (t < 10) stageB((t + 2) % 3, (t + 2) * 64);
        __builtin_amdgcn_s_setprio(1);
#pragma unroll
        for (int mf = 0; mf < 2; ++mf)
#pragma unroll
            for (int nf = 0; nf < 4; ++nf) {
                acc[mf][nf + 5] = MFMA16(af[mf][0], bfh[nf][0], acc[mf][nf + 5], 0, 0, 0);
                acc[mf][nf + 5] = MFMA16(af[mf][1], bfh[nf][1], acc[mf][nf + 5], 0, 0, 0);
            }
        __builtin_amdgcn_s_setprio(0);
        // drain stage(t+1), keep stage(t+2) in flight -> tile t+1 resident
        if (t < 10) {
            if (wv < 4) asm volatile("s_waitcnt vmcnt(7)" ::: "memory");
            else        asm volatile("s_waitcnt vmcnt(6)" ::: "memory");
            __builtin_amdgcn_s_barrier();
        } else if (t == 10) {
            asm volatile("s_waitcnt vmcnt(0)" ::: "memory");
            __builtin_amdgcn_s_barrier();
        }
    }

    // ---------------- epilogue ----------------
    const int bI = m0 >> 10, nn0 = m0 & 1023;
    // q/k frags: direct stores (frags never straddle q/k/v; 768 % 16 == 0)
#pragma unroll
    for (int nf = 0; nf < 9; ++nf) {
        const int ct = n0 + wn * 144 + nf * 16;
        if (ct < 1536) {
            const int which = (ct >= 768) ? 1 : 0;
            const int h = (ct - which * 768) >> 6;
            const int hd = (ct & 63) + l16;
            short* dst = (which ? kb : qb) + (bI * 12 + h) * 65536 + hd;
#pragma unroll
            for (int mf = 0; mf < 2; ++mf)
#pragma unroll
                for (int r = 0; r < 4; ++r) {
                    const int nn = nn0 + wm * 32 + mf * 16 + quad * 4 + r;
                    const float val = acc[mf][nf][r];
                    dst[nn * 64] = bf16_of(which ? val : val * QSCALE);
                }
        }
    }
    // v frags: transpose through LDS in 96-col passes (96 x 136 shorts)
    const int vstart = (n0 >= 1536) ? n0 : 1536;
    const int npass = (n0 + 288 > vstart) ? (n0 + 288 - vstart) / 96 : 0;
    for (int p = 0; p < npass; ++p) {
        __syncthreads();
        const int c0 = vstart + p * 96;
#pragma unroll
        for (int nf = 0; nf < 9; ++nf) {
            const int ct = n0 + wn * 144 + nf * 16;
            if (ct >= c0 && ct < c0 + 96) {
                const int lc = ct - c0 + l16;
#pragma unroll
                for (int mf = 0; mf < 2; ++mf)
#pragma unroll
                    for (int r = 0; r < 4; ++r) {
                        const int rl = wm * 32 + mf * 16 + quad * 4 + r;
                        lds[lc * 136 + rl] = bf16_of(acc[mf][nf][r]);
                    }
            }
        }
        __syncthreads();
        const int vg0 = c0 - 1536;
#pragma unroll
        for (int u = 0; u < 3; ++u) {
            const int idx = u * 512 + tid;       // 96 cols x 16 chunks
            const int lc = idx >> 4, ck = idx & 15;
            const int vg = vg0 + lc;
            const int h = vg >> 6, hd = vg & 63;
            bf8 vv = *(const bf8*)(lds + lc * 136 + ck * 8);
            *(bf8*)(vt + ((bI * 12 + h) * 64 + hd) * 1024 + nn0 + ck * 8) = vv;
        }
    }
}

// ---- final projection: [8192,768] @ [768,768] + bias -> fp32 out ----
__global__ __launch_bounds__(256) void k_gemm_final(
        const short* __restrict__ attn, const short* __restrict__ wtm,
        const float* __restrict__ bias, float* __restrict__ out) {
    __shared__ short smem[32768];
    const int lane = threadIdx.x & 63;
    const int l16 = lane & 15, quad = lane >> 4;
    const int wm = (threadIdx.x >> 6) & 1, wn = threadIdx.x >> 7;
    const int m0 = blockIdx.y * 128, n0 = blockIdx.x * 128;
    f4 z = {0.f, 0.f, 0.f, 0.f};
    f4 acc[4][4] = {{z,z,z,z},{z,z,z,z},{z,z,z,z},{z,z,z,z}};
    gemm128(attn + m0 * 768, wtm + n0 * 768, smem, acc);
#pragma unroll
    for (int mt = 0; mt < 4; ++mt) {
#pragma unroll
        for (int r = 0; r < 4; ++r) {
            const int row = m0 + wm * 64 + mt * 16 + quad * 4 + r;
#pragma unroll
            for (int nt = 0; nt < 4; ++nt) {
                const int e = n0 + wn * 64 + nt * 16 + l16;
                out[row * 768 + e] = acc[mt][nt][r] + bias[e];
            }
        }
    }
}

// ---- flash attention: 4 waves x 32 q-rows (256-thread block), grid (96,8)
//      = 768 blocks -> exactly 3 co-resident blocks/CU (launch_bounds(256,3)).
// Two q-groups per wave SHARE the K and V LDS fragments: ds_read per MFMA
// halves, per-wave ILP doubles, barrier cost per unit work halves.
// S-MFMA set A uses K rows sigma(p)=8*(p>>2)+(p&3), set B rows sigma(p)+4.
// lane(l16,quad) regs [A0..A3,B0..B3] = P[m=l16][j=quad*8+0..7]: the PV
// B-operand directly -- no cross-lane transform needed.
// LDS swizzle f(row)=4*((row>>3)&1)+(row&3) keeps sigma-reads at 2 lanes/bank.
__global__ __launch_bounds__(256, 3) void k_attn(const short* __restrict__ qb,
                                                 const short* __restrict__ kb,
                                                 const short* __restrict__ vt,
                                                 short* __restrict__ attn) {
    __shared__ short Ks[2][4096];     // [64 keys][8 slots], f-swizzled
    __shared__ short Vs[2][4096];     // [64 dims][8 slots], f-swizzled
    const int tid = threadIdx.x, wave = tid >> 6, lane = tid & 63;
    const int l16 = lane & 15, quad = lane >> 4;
    const int bh = blockIdx.x;             // b*12 + h
    const int b = bh / 12, h = bh - b * 12;
    const int m_base = blockIdx.y * 128 + wave * 32;  // 32 q-rows per wave
    const short* qh = qb + bh * 65536;
    const short* kh = kb + bh * 65536;
    const short* vh = vt + bh * 65536;     // [64][1024]

    // K-read offsets: set A row rA = sigma(l16), set B row rA+4 (f identical)
    const int rA = ((l16 >> 2) << 3) + (l16 & 3);
    const int fK = (((rA >> 3) & 1) << 2) + (rA & 3);
    const int sK = (quad ^ fK) * 8;              // slot*8 for d-chunk=quad
    const int oAlo = rA * 64 + sK;               // d 0..31
    const int oAhi = rA * 64 + (sK ^ 32);        // d 32..63 (slot^4)
    const int oBlo = oAlo + 256, oBhi = oAhi + 256;  // row+4
    // V-read offset: row = dt*16+l16, chunk = (jj>>3)+quad
    const int fV = (((l16 >> 3) & 1) << 2) + (l16 & 3);
    const int oV = l16 * 64 + ((quad ^ fV) * 8); // jj=32 -> ^32

    // Q^T b-frags for both 16-row groups (fixed for whole loop)
    const short* qp0 = qh + (m_base + l16) * 64 + quad * 8;
    bf8 qf00 = *(const bf8*)(qp0);
    bf8 qf01 = *(const bf8*)(qp0 + 32);
    const short* qp1 = qp0 + 16 * 64;
    bf8 qf10 = *(const bf8*)(qp1);
    bf8 qf11 = *(const bf8*)(qp1 + 32);

    union { bf8 v; short h[8]; } onef;
#pragma unroll
    for (int i = 0; i < 8; ++i) onef.h[i] = (short)0x3F80;  // bf16 1.0

    f4 z = {0.f, 0.f, 0.f, 0.f};
    f4 acc0[4] = {z, z, z, z};             // out^T group 0: 4 d-tiles
    f4 acc1[4] = {z, z, z, z};             // out^T group 1
    f4 accl0 = z, accl1 = z;               // P row-sums via ones-MFMA

    auto stage = [&](int buf, int j0) {
        // 256 threads x 2: 512 chunks each for K and V
#pragma unroll
        for (int j = 0; j < 2; ++j) {
            int idx = j * 256 + tid;
            int row = idx >> 3;
            int fr = (((row >> 3) & 1) << 2) + (row & 3);
            int gc = (idx & 7) ^ fr;        // slot idx&7 holds chunk gc
            async16(kh + (j0 + row) * 64 + gc * 8, Ks[buf] + idx * 8);
            async16(vh + row * 1024 + j0 + gc * 8, Vs[buf] + idx * 8);
        }
    };

    stage(0, 0);
    int cur = 0;
    for (int it = 0; it < 16; ++it) {
        __builtin_amdgcn_s_waitcnt(0);         // own DMA for tile[cur] drained
        __syncthreads();                       // => tile[cur] resident for all
        if (it + 1 < 16) stage(cur ^ 1, (it + 1) * 64);  // overlaps compute
        const short* Kc = Ks[cur];
        const short* Vc = Vs[cur];

#pragma unroll
        for (int jj = 0; jj < 64; jj += 32) {
            const short* kjj = Kc + jj * 64;
            bf8 kAlo = *(const bf8*)(kjj + oAlo);
            bf8 kAhi = *(const bf8*)(kjj + oAhi);
            bf8 kBlo = *(const bf8*)(kjj + oBlo);
            bf8 kBhi = *(const bf8*)(kjj + oBhi);
            bf8 vf0 = *(const bf8*)(Vc + 0 * 1024 + (oV ^ (jj ? 32 : 0)));
            bf8 vf1 = *(const bf8*)(Vc + 1 * 1024 + (oV ^ (jj ? 32 : 0)));
            bf8 vf2 = *(const bf8*)(Vc + 2 * 1024 + (oV ^ (jj ? 32 : 0)));
            bf8 vf3 = *(const bf8*)(Vc + 3 * 1024 + (oV ^ (jj ? 32 : 0)));

            // ----- group 0 -----
            {
                f4 sA = z, sB = z;
                sA = MFMA16(kAlo, qf00, sA, 0, 0, 0);
                sA = MFMA16(kAhi, qf01, sA, 0, 0, 0);
                sB = MFMA16(kBlo, qf00, sB, 0, 0, 0);
                sB = MFMA16(kBhi, qf01, sB, 0, 0, 0);
                float a0 = __builtin_amdgcn_exp2f(sA[0]);
                float a1 = __builtin_amdgcn_exp2f(sA[1]);
                float a2 = __builtin_amdgcn_exp2f(sA[2]);
                float a3 = __builtin_amdgcn_exp2f(sA[3]);
                float b0 = __builtin_amdgcn_exp2f(sB[0]);
                float b1 = __builtin_amdgcn_exp2f(sB[1]);
                float b2 = __builtin_amdgcn_exp2f(sB[2]);
                float b3 = __builtin_amdgcn_exp2f(sB[3]);
                union { bf8 v; unsigned u[4]; } p;
                p.u[0] = bfpk(a0, a1); p.u[1] = bfpk(a2, a3);
                p.u[2] = bfpk(b0, b1); p.u[3] = bfpk(b2, b3);
                accl0 = MFMA16(onef.v, p.v, accl0, 0, 0, 0);
                acc0[0] = MFMA16(vf0, p.v, acc0[0], 0, 0, 0);
                acc0[1] = MFMA16(vf1, p.v, acc0[1], 0, 0, 0);
                acc0[2] = MFMA16(vf2, p.v, acc0[2], 0, 0, 0);
                acc0[3] = MFMA16(vf3, p.v, acc0[3], 0, 0, 0);
            }
            // ----- group 1 (shares kA/kB/vf frags) -----
            {
                f4 sA = z, sB = z;
                sA = MFMA16(kAlo, qf10, sA, 0, 0, 0);
                sA = MFMA16(kAhi, qf11, sA, 0, 0, 0);
                sB = MFMA16(kBlo, qf10, sB, 0, 0, 0);
                sB = MFMA16(kBhi, qf11, sB, 0, 0, 0);
                float a0 = __builtin_amdgcn_exp2f(sA[0]);
                float a1 = __builtin_amdgcn_exp2f(sA[1]);
                float a2 = __builtin_amdgcn_exp2f(sA[2]);
                float a3 = __builtin_amdgcn_exp2f(sA[3]);
                float b0 = __builtin_amdgcn_exp2f(sB[0]);
                float b1 = __builtin_amdgcn_exp2f(sB[1]);
                float b2 = __builtin_amdgcn_exp2f(sB[2]);
                float b3 = __builtin_amdgcn_exp2f(sB[3]);
                union { bf8 v; unsigned u[4]; } p;
                p.u[0] = bfpk(a0, a1); p.u[1] = bfpk(a2, a3);
                p.u[2] = bfpk(b0, b1); p.u[3] = bfpk(b2, b3);
                accl1 = MFMA16(onef.v, p.v, accl1, 0, 0, 0);
                acc1[0] = MFMA16(vf0, p.v, acc1[0], 0, 0, 0);
                acc1[1] = MFMA16(vf1, p.v, acc1[1], 0, 0, 0);
                acc1[2] = MFMA16(vf2, p.v, acc1[2], 0, 0, 0);
                acc1[3] = MFMA16(vf3, p.v, acc1[3], 0, 0, 0);
            }
        }
        cur ^= 1;
    }

    const float inv0 = 1.f / accl0[0];
    const float inv1 = 1.f / accl1[0];
    const int row0 = (b << 10) + m_base + l16;
    short* op0 = attn + row0 * 768 + h * 64 + quad * 4;
    short* op1 = op0 + 16 * 768;
#pragma unroll
    for (int dt = 0; dt < 4; ++dt)
#pragma unroll
        for (int r = 0; r < 4; ++r) {
            op0[dt * 16 + r] = bf16_of(acc0[dt][r] * inv0);
            op1[dt * 16 + r] = bf16_of(acc1[dt][r] * inv1);
        }
}

extern "C" void kernel_launch(void* const* d_in, const int* in_sizes, int n_in,
                              void* d_out, int out_size, void* d_ws, size_t ws_size,
                              hipStream_t stream) {
    const float* x    = (const float*)d_in[0];   // [8,1024,768]
    const float* gate = (const float*)d_in[1];   // [8,1024]
    const float* Wqkv = (const float*)d_in[2];   // [768,2304]
    const float* Wmsa = (const float*)d_in[3];   // [768,768]
    const float* bmsa = (const float*)d_in[4];   // [768]
    float* out = (float*)d_out;

    char* ws = (char*)d_ws;
    short* xb  = (short*)(ws);
    short* wtq = (short*)(ws + 12582912);
    short* wtm = (short*)(ws + 16121856);
    short* qb  = (short*)(ws + 17301504);
    short* kb  = (short*)(ws + 29884416);
    short* vt  = (short*)(ws + 42467328);
    short* attn = xb;  // xb fully consumed by k_gemm_qkv before k_attn writes

    k_prep<<<3648, 256, 0, stream>>>(x, gate, xb, Wqkv, wtq, Wmsa, wtm);
    k_gemm_qkv<<<512, 512, 0, stream>>>(xb, wtq, qb, kb, vt);
    k_attn<<<dim3(96, 8), 256, 0, stream>>>(qb, kb, vt, attn);
    k_gemm_final<<<dim3(6, 64), 256, 0, stream>>>(attn, wtm, bmsa, out);
}

// Round 8
// 178.266 us; speedup vs baseline: 1.1855x; 1.0461x over previous
//
#include <hip/hip_runtime.h>
#include <hip/hip_bf16.h>

// Shapes: B=8, N=1024, D=768, H=12, HD=64, 3D=2304, tokens M=8192.
// Workspace layout (bytes), total 55,050,240 (~52.5 MiB):
//   xb   @ 0         : [8192][768]  bf16 (x * gate; reused as attn-out later)
//   wtq  @ 12582912  : [2304][768]  bf16 (W_qkv^T)
//   wtm  @ 16121856  : [768][768]   bf16 (W_msa^T)
//   qb   @ 17301504  : [B,H,N,64]   bf16 (q * SCALE * log2e)
//   kb   @ 29884416  : [B,H,N,64]   bf16 (k)
//   vt   @ 42467328  : [B,H,64,N]   bf16 (v, transposed)

typedef __attribute__((ext_vector_type(8))) short bf8;   // 8 x bf16 (4 VGPRs)
typedef __attribute__((ext_vector_type(4))) float f4;

#define QSCALE 0.1803368801111204f  // (1/8) * log2(e): exp2-domain logits
#define MFMA16 __builtin_amdgcn_mfma_f32_16x16x32_bf16

static __device__ __forceinline__ short bf16_of(float f) {
    union { float f; unsigned u; } a; a.f = f;
    unsigned r = a.u + 0x7FFFu + ((a.u >> 16) & 1u);  // RNE
    return (short)(r >> 16);
}

static __device__ __forceinline__ unsigned bfpk(float lo, float hi) {
    float2 t; t.x = lo; t.y = hi;
    __hip_bfloat162 b = __float22bfloat162_rn(t);
    union { __hip_bfloat162 b; unsigned u; } c; c.b = b;
    return c.u;
}

// async global->LDS, 16 bytes/lane. LDS dest must be wave-uniform base + lane*16.
static __device__ __forceinline__ void async16(const short* g, short* l) {
    __builtin_amdgcn_global_load_lds(
        (const __attribute__((address_space(1))) void*)g,
        (__attribute__((address_space(3))) void*)l, 16, 0, 0);
}

// ---- merged prep kernel: cvt (blocks 0..3071) + Wqkv transpose (3072..3503)
//      + Wmsa transpose (3504..3647). Independent work; saves 2 launch gaps.
static __device__ __forceinline__ void transpose64(
        const float* __restrict__ w, short* __restrict__ wt,
        int K, int E, int k0, int e0, int tid, short (*t)[65]) {
#pragma unroll
    for (int p = 0; p < 16; ++p) {
        int idx = p * 256 + tid;
        int r = idx >> 6, c = idx & 63;
        t[r][c] = bf16_of(w[(k0 + r) * E + e0 + c]);
    }
    __syncthreads();
#pragma unroll
    for (int p = 0; p < 16; ++p) {
        int idx = p * 256 + tid;
        int r = idx >> 6, c = idx & 63;     // r = e offset, c = k offset
        wt[(e0 + r) * K + k0 + c] = t[c][r];
    }
}

__global__ __launch_bounds__(256) void k_prep(
        const float* __restrict__ x, const float* __restrict__ gate,
        short* __restrict__ xb,
        const float* __restrict__ Wqkv, short* __restrict__ wtq,
        const float* __restrict__ Wmsa, short* __restrict__ wtm) {
    __shared__ short t[64][65];
    const int bid = blockIdx.x, tid = threadIdx.x;
    if (bid < 3072) {
        int i = bid * 256 + tid;              // 786432 = 8192*768/8 exactly
        const float g = gate[i / 96];         // row = i*8/768
        const f4* sp = (const f4*)x;
        f4 a = sp[2 * i], b = sp[2 * i + 1];
        union { bf8 v; short h[8]; } o;
        o.h[0] = bf16_of(a[0] * g); o.h[1] = bf16_of(a[1] * g);
        o.h[2] = bf16_of(a[2] * g); o.h[3] = bf16_of(a[3] * g);
        o.h[4] = bf16_of(b[0] * g); o.h[5] = bf16_of(b[1] * g);
        o.h[6] = bf16_of(b[2] * g); o.h[7] = bf16_of(b[3] * g);
        ((bf8*)xb)[i] = o.v;
    } else if (bid < 3504) {
        int tt = bid - 3072;                  // 432 = 36 x 12
        transpose64(Wqkv, wtq, 768, 2304, (tt / 36) * 64, (tt % 36) * 64, tid, t);
    } else {
        int tt = bid - 3504;                  // 144 = 12 x 12
        transpose64(Wmsa, wtm, 768, 768, (tt / 12) * 64, (tt % 12) * 64, tid, t);
    }
}

// ---- 128x128 2-phase GEMM mainloop (kept for k_gemm_final: its 384 blocks
// are fully co-resident at 2 blocks/CU).
static __device__ __forceinline__ void gemm128(const short* __restrict__ gA,
                                               const short* __restrict__ gB,
                                               short* smem,
                                               f4 acc[4][4]) {
    const int tid = threadIdx.x, lane = tid & 63;
    const int l16 = lane & 15, quad = lane >> 4, rx = l16 & 7;
    const int wm = (tid >> 6) & 1, wn = tid >> 7;

    auto stage = [&](short* S, int k0) {
#pragma unroll
        for (int c = 0; c < 4; ++c) {
            int p = c * 256 + tid;
            int row = p >> 3, slot = p & 7;
            int gc = slot ^ (row & 7);
            async16(gA + row * 768 + k0 + gc * 8, S + p * 8);
            async16(gB + row * 768 + k0 + gc * 8, S + 8192 + p * 8);
        }
    };

    stage(smem, 0);
    for (int it = 0; it < 12; ++it) {
        __builtin_amdgcn_s_waitcnt(0);   // own DMA for tile[it] drained
        __syncthreads();                 // => tile[it] resident for all waves
        short* Sc = smem + (it & 1) * 16384;
        if (it + 1 < 12) stage(smem + ((it + 1) & 1) * 16384, (it + 1) * 64);
        const short* As = Sc;
        const short* Bs = Sc + 8192;
#pragma unroll
        for (int ks = 0; ks < 2; ++ks) {
            bf8 af[4], bfr[4];
#pragma unroll
            for (int mt = 0; mt < 4; ++mt)
                af[mt] = *(const bf8*)(As + (wm * 64 + mt * 16 + l16) * 64 +
                                       (((ks * 4 + quad) ^ rx) * 8));
#pragma unroll
            for (int nt = 0; nt < 4; ++nt)
                bfr[nt] = *(const bf8*)(Bs + (wn * 64 + nt * 16 + l16) * 64 +
                                        (((ks * 4 + quad) ^ rx) * 8));
#pragma unroll
            for (int mt = 0; mt < 4; ++mt)
#pragma unroll
                for (int nt = 0; nt < 4; ++nt)
                    acc[mt][nt] = MFMA16(af[mt], bfr[nt], acc[mt][nt], 0, 0, 0);
        }
    }
    __syncthreads();   // callers may reuse smem right after return
}

// ---- QKV projection: [8192,768] @ [768,2304], tile 128x144, BK=64.
// ROUND-7 LESSON: the 128-reg trap is 512-thread-specific. A 256-THREAD block
// at 2 blocks/CU is only 8 waves/CU = 2 waves/SIMD -> FULL 256-reg budget per
// wave, AND two independent blocks per CU cross-hide each other's per-tile
// drain stalls (the m97 mechanism; our R7 1-block/CU config had no partner).
// Geometry: 4 waves as 4M x 1N -> per-wave 32x144 = acc[2][9] = 72 AGPR; peak
// frag 56 VGPR (nf-split 5+4); no spill at 256 budget.
// Grid 64m x 16n = 1024 blocks = exactly 4 blocks per CU: zero tail, zero
// imbalance. LDS double buffer 2 x 17408 shorts = 68 KiB -> 2 blocks/CU.
// Schedule per K-tile (12 tiles): read af+bfr(0-4) | stage A(t+1) | 20 MFMA |
// read bfh(5-8) | stage B(t+1) | 16 MFMA | vmcnt(0) | barrier. Stage lands in
// the OTHER buffer; in-order issue + MFMA lgkm deps make reads-before-barrier
// safe (same protocol as R7, refcheck-passed).
// Proven slot^(row&7) XOR swizzle (2 lanes/bank on ds_read_b128).
__global__ __launch_bounds__(256, 2) void k_gemm_qkv(
        const short* __restrict__ xb, const short* __restrict__ wtq,
        short* __restrict__ qb, short* __restrict__ kb, short* __restrict__ vt) {
    __shared__ short lds[34816];   // 2 x 17408 shorts = 68 KiB
    const int tid = threadIdx.x, lane = tid & 63;
    const int l16 = lane & 15, quad = lane >> 4, rx = l16 & 7;
    const int wm = tid >> 6;       // 4 M-waves; every wave covers all 144 cols

    // XCD swizzle: 1024 blocks = 8 XCDs x 128; each XCD: 8 mI x all 16 nI
    // (B 3.5 MB ~ one XCD L2; A 8x128 rows = 1.6 MB).
    const int wg = blockIdx.x;
    const int swz = (wg & 7) * 128 + (wg >> 3);
    const int mI = swz >> 4, nI = swz & 15;
    const int m0 = mI * 128, n0 = nI * 144;

    const short* gA = xb + m0 * 768;
    const short* gB = wtq + n0 * 768;

    auto stageA = [&](int buf, int k0) {        // 128x64 = 1024 chunks, 4/thr
        short* base = lds + buf * 17408;
#pragma unroll
        for (int j = 0; j < 4; ++j) {
            int p = j * 256 + tid, row = p >> 3;
            int gc = (p & 7) ^ (row & 7);
            async16(gA + row * 768 + k0 + gc * 8, base + p * 8);
        }
    };
    auto stageB = [&](int buf, int k0) {        // 144x64 = 1152 chunks
        short* base = lds + buf * 17408 + 8192;
#pragma unroll
        for (int j = 0; j < 4; ++j) {
            int p = j * 256 + tid, row = p >> 3;
            int gc = (p & 7) ^ (row & 7);
            async16(gB + row * 768 + k0 + gc * 8, base + p * 8);
        }
        if (tid < 128) {            // waves 0,1 take the extra 128 chunks
            int p = 1024 + tid, row = p >> 3;
            int gc = (p & 7) ^ (row & 7);
            async16(gB + row * 768 + k0 + gc * 8, base + p * 8);
        }
    };

    auto rdA = [&](const short* base, int mf, int ks) {
        return *(const bf8*)(base + (wm * 32 + mf * 16 + l16) * 64 +
                             (((ks * 4 + quad) ^ rx) << 3));
    };
    auto rdB = [&](const short* base, int nf, int ks) {
        return *(const bf8*)(base + 8192 + (nf * 16 + l16) * 64 +
                             (((ks * 4 + quad) ^ rx) << 3));
    };

    f4 z = {0.f, 0.f, 0.f, 0.f};
    f4 acc[2][9];
#pragma unroll
    for (int mf = 0; mf < 2; ++mf)
#pragma unroll
        for (int nf = 0; nf < 9; ++nf) acc[mf][nf] = z;

    stageA(0, 0); stageB(0, 0);
    asm volatile("s_waitcnt vmcnt(0)" ::: "memory");
    __builtin_amdgcn_s_barrier();

#pragma unroll 2
    for (int t = 0; t < 12; ++t) {
        const short* cur = lds + (t & 1) * 17408;
        // ---- phase 1: nf 0-4 ----
        bf8 af[2][2];
        af[0][0] = rdA(cur, 0, 0); af[0][1] = rdA(cur, 0, 1);
        af[1][0] = rdA(cur, 1, 0); af[1][1] = rdA(cur, 1, 1);
        bf8 bfr[5][2];
#pragma unroll
        for (int nf = 0; nf < 5; ++nf) { bfr[nf][0] = rdB(cur, nf, 0); bfr[nf][1] = rdB(cur, nf, 1); }
        if (t < 11) stageA((t + 1) & 1, (t + 1) * 64);
        __builtin_amdgcn_s_setprio(1);
#pragma unroll
        for (int mf = 0; mf < 2; ++mf)
#pragma unroll
            for (int nf = 0; nf < 5; ++nf) {
                acc[mf][nf] = MFMA16(af[mf][0], bfr[nf][0], acc[mf][nf], 0, 0, 0);
                acc[mf][nf] = MFMA16(af[mf][1], bfr[nf][1], acc[mf][nf], 0, 0, 0);
            }
        __builtin_amdgcn_s_setprio(0);
        // ---- phase 2: nf 5-8 ----
        bf8 bfh[4][2];
#pragma unroll
        for (int nf = 0; nf < 4; ++nf) { bfh[nf][0] = rdB(cur, nf + 5, 0); bfh[nf][1] = rdB(cur, nf + 5, 1); }
        if (t < 11) stageB((t + 1) & 1, (t + 1) * 64);
        __builtin_amdgcn_s_setprio(1);
#pragma unroll
        for (int mf = 0; mf < 2; ++mf)
#pragma unroll
            for (int nf = 0; nf < 4; ++nf) {
                acc[mf][nf + 5] = MFMA16(af[mf][0], bfh[nf][0], acc[mf][nf + 5], 0, 0, 0);
                acc[mf][nf + 5] = MFMA16(af[mf][1], bfh[nf][1], acc[mf][nf + 5], 0, 0, 0);
            }
        __builtin_amdgcn_s_setprio(0);
        // drain own stage(t+1) -> next buffer resident after barrier; the
        // co-resident second block on this CU hides the drain stall.
        asm volatile("s_waitcnt vmcnt(0)" ::: "memory");
        __builtin_amdgcn_s_barrier();
    }

    // ---------------- epilogue ----------------
    const int bI = m0 >> 10, nn0 = m0 & 1023;
    // q/k frags: direct stores (frags never straddle q/k/v; 768 % 16 == 0)
#pragma unroll
    for (int nf = 0; nf < 9; ++nf) {
        const int ct = n0 + nf * 16;
        if (ct < 1536) {
            const int which = (ct >= 768) ? 1 : 0;
            const int h = (ct - which * 768) >> 6;
            const int hd = (ct & 63) + l16;
            short* dst = (which ? kb : qb) + (bI * 12 + h) * 65536 + hd;
#pragma unroll
            for (int mf = 0; mf < 2; ++mf)
#pragma unroll
                for (int r = 0; r < 4; ++r) {
                    const int nn = nn0 + wm * 32 + mf * 16 + quad * 4 + r;
                    const float val = acc[mf][nf][r];
                    dst[nn * 64] = bf16_of(which ? val : val * QSCALE);
                }
        }
    }
    // v frags: transpose through LDS in 48-col passes (48 x 136 shorts).
    // v-count per block is 0, 48 (nI==10: cols 1536..1583) or 144 (nI>=11);
    // all acc[] indices below are compile-time (rule #20), runtime only in
    // the range conditions.
    const int vlo = (n0 >= 1536) ? n0 : 1536;
    const int vcnt = n0 + 144 - vlo;
    const int npass = (vcnt > 0) ? vcnt / 48 : 0;
    for (int p = 0; p < npass; ++p) {
        __syncthreads();
        const int c0 = vlo + p * 48;
#pragma unroll
        for (int nf = 0; nf < 9; ++nf) {
            const int ct = n0 + nf * 16;
            if (ct >= c0 && ct < c0 + 48) {
                const int lcol = ct - c0 + l16;        // 0..47
#pragma unroll
                for (int mf = 0; mf < 2; ++mf)
#pragma unroll
                    for (int r = 0; r < 4; ++r) {
                        const int row = wm * 32 + mf * 16 + quad * 4 + r;
                        lds[lcol * 136 + row] = bf16_of(acc[mf][nf][r]);
                    }
            }
        }
        __syncthreads();
        const int vg0 = c0 - 1536;
#pragma unroll
        for (int u = 0; u < 3; ++u) {
            const int idx = u * 256 + tid;     // 48 cols x 16 chunks = 768
            const int lc = idx >> 4, ck = idx & 15;
            const int vg = vg0 + lc;
            const int h = vg >> 6, hd = vg & 63;
            bf8 vv = *(const bf8*)(lds + lc * 136 + ck * 8);
            *(bf8*)(vt + ((bI * 12 + h) * 64 + hd) * 1024 + nn0 + ck * 8) = vv;
        }
    }
}

// ---- final projection: [8192,768] @ [768,768] + bias -> fp32 out ----
__global__ __launch_bounds__(256) void k_gemm_final(
        const short* __restrict__ attn, const short* __restrict__ wtm,
        const float* __restrict__ bias, float* __restrict__ out) {
    __shared__ short smem[32768];
    const int lane = threadIdx.x & 63;
    const int l16 = lane & 15, quad = lane >> 4;
    const int wm = (threadIdx.x >> 6) & 1, wn = threadIdx.x >> 7;
    const int m0 = blockIdx.y * 128, n0 = blockIdx.x * 128;
    f4 z = {0.f, 0.f, 0.f, 0.f};
    f4 acc[4][4] = {{z,z,z,z},{z,z,z,z},{z,z,z,z},{z,z,z,z}};
    gemm128(attn + m0 * 768, wtm + n0 * 768, smem, acc);
#pragma unroll
    for (int mt = 0; mt < 4; ++mt) {
#pragma unroll
        for (int r = 0; r < 4; ++r) {
            const int row = m0 + wm * 64 + mt * 16 + quad * 4 + r;
#pragma unroll
            for (int nt = 0; nt < 4; ++nt) {
                const int e = n0 + wn * 64 + nt * 16 + l16;
                out[row * 768 + e] = acc[mt][nt][r] + bias[e];
            }
        }
    }
}

// ---- flash attention: 4 waves x 32 q-rows (256-thread block), grid (96,8)
//      = 768 blocks -> exactly 3 co-resident blocks/CU (launch_bounds(256,3)).
// Two q-groups per wave SHARE the K and V LDS fragments: ds_read per MFMA
// halves, per-wave ILP doubles, barrier cost per unit work halves.
// S-MFMA set A uses K rows sigma(p)=8*(p>>2)+(p&3), set B rows sigma(p)+4.
// lane(l16,quad) regs [A0..A3,B0..B3] = P[m=l16][j=quad*8+0..7]: the PV
// B-operand directly -- no cross-lane transform needed.
// LDS swizzle f(row)=4*((row>>3)&1)+(row&3) keeps sigma-reads at 2 lanes/bank.
__global__ __launch_bounds__(256, 3) void k_attn(const short* __restrict__ qb,
                                                 const short* __restrict__ kb,
                                                 const short* __restrict__ vt,
                                                 short* __restrict__ attn) {
    __shared__ short Ks[2][4096];     // [64 keys][8 slots], f-swizzled
    __shared__ short Vs[2][4096];     // [64 dims][8 slots], f-swizzled
    const int tid = threadIdx.x, wave = tid >> 6, lane = tid & 63;
    const int l16 = lane & 15, quad = lane >> 4;
    const int bh = blockIdx.x;             // b*12 + h
    const int b = bh / 12, h = bh - b * 12;
    const int m_base = blockIdx.y * 128 + wave * 32;  // 32 q-rows per wave
    const short* qh = qb + bh * 65536;
    const short* kh = kb + bh * 65536;
    const short* vh = vt + bh * 65536;     // [64][1024]

    // K-read offsets: set A row rA = sigma(l16), set B row rA+4 (f identical)
    const int rA = ((l16 >> 2) << 3) + (l16 & 3);
    const int fK = (((rA >> 3) & 1) << 2) + (rA & 3);
    const int sK = (quad ^ fK) * 8;              // slot*8 for d-chunk=quad
    const int oAlo = rA * 64 + sK;               // d 0..31
    const int oAhi = rA * 64 + (sK ^ 32);        // d 32..63 (slot^4)
    const int oBlo = oAlo + 256, oBhi = oAhi + 256;  // row+4
    // V-read offset: row = dt*16+l16, chunk = (jj>>3)+quad
    const int fV = (((l16 >> 3) & 1) << 2) + (l16 & 3);
    const int oV = l16 * 64 + ((quad ^ fV) * 8); // jj=32 -> ^32

    // Q^T b-frags for both 16-row groups (fixed for whole loop)
    const short* qp0 = qh + (m_base + l16) * 64 + quad * 8;
    bf8 qf00 = *(const bf8*)(qp0);
    bf8 qf01 = *(const bf8*)(qp0 + 32);
    const short* qp1 = qp0 + 16 * 64;
    bf8 qf10 = *(const bf8*)(qp1);
    bf8 qf11 = *(const bf8*)(qp1 + 32);

    union { bf8 v; short h[8]; } onef;
#pragma unroll
    for (int i = 0; i < 8; ++i) onef.h[i] = (short)0x3F80;  // bf16 1.0

    f4 z = {0.f, 0.f, 0.f, 0.f};
    f4 acc0[4] = {z, z, z, z};             // out^T group 0: 4 d-tiles
    f4 acc1[4] = {z, z, z, z};             // out^T group 1
    f4 accl0 = z, accl1 = z;               // P row-sums via ones-MFMA

    auto stage = [&](int buf, int j0) {
        // 256 threads x 2: 512 chunks each for K and V
#pragma unroll
        for (int j = 0; j < 2; ++j) {
            int idx = j * 256 + tid;
            int row = idx >> 3;
            int fr = (((row >> 3) & 1) << 2) + (row & 3);
            int gc = (idx & 7) ^ fr;        // slot idx&7 holds chunk gc
            async16(kh + (j0 + row) * 64 + gc * 8, Ks[buf] + idx * 8);
            async16(vh + row * 1024 + j0 + gc * 8, Vs[buf] + idx * 8);
        }
    };

    stage(0, 0);
    int cur = 0;
    for (int it = 0; it < 16; ++it) {
        __builtin_amdgcn_s_waitcnt(0);         // own DMA for tile[cur] drained
        __syncthreads();                       // => tile[cur] resident for all
        if (it + 1 < 16) stage(cur ^ 1, (it + 1) * 64);  // overlaps compute
        const short* Kc = Ks[cur];
        const short* Vc = Vs[cur];

#pragma unroll
        for (int jj = 0; jj < 64; jj += 32) {
            const short* kjj = Kc + jj * 64;
            bf8 kAlo = *(const bf8*)(kjj + oAlo);
            bf8 kAhi = *(const bf8*)(kjj + oAhi);
            bf8 kBlo = *(const bf8*)(kjj + oBlo);
            bf8 kBhi = *(const bf8*)(kjj + oBhi);
            bf8 vf0 = *(const bf8*)(Vc + 0 * 1024 + (oV ^ (jj ? 32 : 0)));
            bf8 vf1 = *(const bf8*)(Vc + 1 * 1024 + (oV ^ (jj ? 32 : 0)));
            bf8 vf2 = *(const bf8*)(Vc + 2 * 1024 + (oV ^ (jj ? 32 : 0)));
            bf8 vf3 = *(const bf8*)(Vc + 3 * 1024 + (oV ^ (jj ? 32 : 0)));

            // ----- group 0 -----
            {
                f4 sA = z, sB = z;
                sA = MFMA16(kAlo, qf00, sA, 0, 0, 0);
                sA = MFMA16(kAhi, qf01, sA, 0, 0, 0);
                sB = MFMA16(kBlo, qf00, sB, 0, 0, 0);
                sB = MFMA16(kBhi, qf01, sB, 0, 0, 0);
                float a0 = __builtin_amdgcn_exp2f(sA[0]);
                float a1 = __builtin_amdgcn_exp2f(sA[1]);
                float a2 = __builtin_amdgcn_exp2f(sA[2]);
                float a3 = __builtin_amdgcn_exp2f(sA[3]);
                float b0 = __builtin_amdgcn_exp2f(sB[0]);
                float b1 = __builtin_amdgcn_exp2f(sB[1]);
                float b2 = __builtin_amdgcn_exp2f(sB[2]);
                float b3 = __builtin_amdgcn_exp2f(sB[3]);
                union { bf8 v; unsigned u[4]; } p;
                p.u[0] = bfpk(a0, a1); p.u[1] = bfpk(a2, a3);
                p.u[2] = bfpk(b0, b1); p.u[3] = bfpk(b2, b3);
                accl0 = MFMA16(onef.v, p.v, accl0, 0, 0, 0);
                acc0[0] = MFMA16(vf0, p.v, acc0[0], 0, 0, 0);
                acc0[1] = MFMA16(vf1, p.v, acc0[1], 0, 0, 0);
                acc0[2] = MFMA16(vf2, p.v, acc0[2], 0, 0, 0);
                acc0[3] = MFMA16(vf3, p.v, acc0[3], 0, 0, 0);
            }
            // ----- group 1 (shares kA/kB/vf frags) -----
            {
                f4 sA = z, sB = z;
                sA = MFMA16(kAlo, qf10, sA, 0, 0, 0);
                sA = MFMA16(kAhi, qf11, sA, 0, 0, 0);
                sB = MFMA16(kBlo, qf10, sB, 0, 0, 0);
                sB = MFMA16(kBhi, qf11, sB, 0, 0, 0);
                float a0 = __builtin_amdgcn_exp2f(sA[0]);
                float a1 = __builtin_amdgcn_exp2f(sA[1]);
                float a2 = __builtin_amdgcn_exp2f(sA[2]);
                float a3 = __builtin_amdgcn_exp2f(sA[3]);
                float b0 = __builtin_amdgcn_exp2f(sB[0]);
                float b1 = __builtin_amdgcn_exp2f(sB[1]);
                float b2 = __builtin_amdgcn_exp2f(sB[2]);
                float b3 = __builtin_amdgcn_exp2f(sB[3]);
                union { bf8 v; unsigned u[4]; } p;
                p.u[0] = bfpk(a0, a1); p.u[1] = bfpk(a2, a3);
                p.u[2] = bfpk(b0, b1); p.u[3] = bfpk(b2, b3);
                accl1 = MFMA16(onef.v, p.v, accl1, 0, 0, 0);
                acc1[0] = MFMA16(vf0, p.v, acc1[0], 0, 0, 0);
                acc1[1] = MFMA16(vf1, p.v, acc1[1], 0, 0, 0);
                acc1[2] = MFMA16(vf2, p.v, acc1[2], 0, 0, 0);
                acc1[3] = MFMA16(vf3, p.v, acc1[3], 0, 0, 0);
            }
        }
        cur ^= 1;
    }

    const float inv0 = 1.f / accl0[0];
    const float inv1 = 1.f / accl1[0];
    const int row0 = (b << 10) + m_base + l16;
    short* op0 = attn + row0 * 768 + h * 64 + quad * 4;
    short* op1 = op0 + 16 * 768;
#pragma unroll
    for (int dt = 0; dt < 4; ++dt)
#pragma unroll
        for (int r = 0; r < 4; ++r) {
            op0[dt * 16 + r] = bf16_of(acc0[dt][r] * inv0);
            op1[dt * 16 + r] = bf16_of(acc1[dt][r] * inv1);
        }
}

extern "C" void kernel_launch(void* const* d_in, const int* in_sizes, int n_in,
                              void* d_out, int out_size, void* d_ws, size_t ws_size,
                              hipStream_t stream) {
    const float* x    = (const float*)d_in[0];   // [8,1024,768]
    const float* gate = (const float*)d_in[1];   // [8,1024]
    const float* Wqkv = (const float*)d_in[2];   // [768,2304]
    const float* Wmsa = (const float*)d_in[3];   // [768,768]
    const float* bmsa = (const float*)d_in[4];   // [768]
    float* out = (float*)d_out;

    char* ws = (char*)d_ws;
    short* xb  = (short*)(ws);
    short* wtq = (short*)(ws + 12582912);
    short* wtm = (short*)(ws + 16121856);
    short* qb  = (short*)(ws + 17301504);
    short* kb  = (short*)(ws + 29884416);
    short* vt  = (short*)(ws + 42467328);
    short* attn = xb;  // xb fully consumed by k_gemm_qkv before k_attn writes

    k_prep<<<3648, 256, 0, stream>>>(x, gate, xb, Wqkv, wtq, Wmsa, wtm);
    k_gemm_qkv<<<1024, 256, 0, stream>>>(xb, wtq, qb, kb, vt);
    k_attn<<<dim3(96, 8), 256, 0, stream>>>(qb, kb, vt, attn);
    k_gemm_final<<<dim3(6, 64), 256, 0, stream>>>(attn, wtm, bmsa, out);
}